// Round 9
// baseline (197.341 us; speedup 1.0000x reference)
//
#include <hip/hip_runtime.h>
#include <hip/hip_bf16.h>
#include <stdint.h>

#define NQ 2048
#define NKV 2048
#define DIM 1024
#define INNER 1024
#define HEADS 16
#define DH 64
#define BATCH 2

typedef float f32x4 __attribute__((ext_vector_type(4)));
typedef __bf16 bf16x8 __attribute__((ext_vector_type(8)));
typedef unsigned int u32x4 __attribute__((ext_vector_type(4)));

__device__ inline ushort f2b(float f) {
    uint32_t u = __builtin_bit_cast(uint32_t, f);
    u += 0x7fff + ((u >> 16) & 1);   // round-to-nearest-even
    return (ushort)(u >> 16);
}

__device__ inline uint pkbf16(float lo, float hi) {
    __hip_bfloat162 h = __float22bfloat162_rn(make_float2(lo, hi));
    uint r;
    __builtin_memcpy(&r, &h, 4);   // low 16 = bf16(lo), high 16 = bf16(hi)
    return r;
}

__device__ __forceinline__ void gload16(const void* g, void* lds) {
    __builtin_amdgcn_global_load_lds(
        (const __attribute__((address_space(1))) unsigned int*)g,
        (__attribute__((address_space(3))) unsigned int*)lds, 16, 0, 0);
}

// ---------------- fp32 -> bf16 convert: x and ctx fused ----------------
__global__ void cvt2(const float* __restrict__ a, ushort* __restrict__ oa,
                     const float* __restrict__ b, ushort* __restrict__ ob, int n4) {
    int i = blockIdx.x * blockDim.x + threadIdx.x;
    int stride = gridDim.x * blockDim.x;
    for (; i < 2 * n4; i += stride) {
        float4 v;
        if (i < n4) v = ((const float4*)a)[i];
        else        v = ((const float4*)b)[i - n4];
        ushort4 o;
        o.x = f2b(v.x); o.y = f2b(v.y); o.z = f2b(v.z); o.w = f2b(v.w);
        if (i < n4) ((ushort4*)oa)[i] = o;
        else        ((ushort4*)ob)[i - n4] = o;
    }
}

// ---------------- transpose + convert, 4 fused 1024x1024 slices ----------------
__global__ void transp4(const float* __restrict__ Wq, const float* __restrict__ Wkv,
                        const float* __restrict__ Wout,
                        ushort* __restrict__ Wqt, ushort* __restrict__ Wkvt,
                        ushort* __restrict__ Woutt) {
    __shared__ ushort tile[32][33];
    int z = blockIdx.z;
    const float* src; ushort* dst; int C;
    if (z == 0)      { src = Wq;          dst = Wqt;                C = 1024; }
    else if (z == 1) { src = Wkv;         dst = Wkvt;               C = 2048; }
    else if (z == 2) { src = Wkv + 1024;  dst = Wkvt + 1024 * 1024; C = 2048; }
    else             { src = Wout;        dst = Woutt;              C = 1024; }
    int c0 = blockIdx.x * 32, r0 = blockIdx.y * 32;
    int tx = threadIdx.x, ty = threadIdx.y;   // 32 x 8
#pragma unroll
    for (int i = 0; i < 4; i++)
        tile[ty + i * 8][tx] = f2b(src[(size_t)(r0 + ty + i * 8) * C + c0 + tx]);
    __syncthreads();
#pragma unroll
    for (int i = 0; i < 4; i++)
        dst[(size_t)(c0 + ty + i * 8) * 1024 + r0 + tx] = tile[tx][ty + i * 8];
}

// ---------------- bf16 transpose V: vb[b][kv][h*64+d] -> vtb[b][h][d][kv] ----------------
__global__ __launch_bounds__(256) void vtransp(const ushort* __restrict__ vb, ushort* __restrict__ vtb) {
    __shared__ ushort tile[64][72];
    int kt = blockIdx.x, h = blockIdx.y, b = blockIdx.z;
    int t = threadIdx.x;
    const ushort* src = vb + ((size_t)b * NKV + kt * 64) * INNER + h * DH;
#pragma unroll
    for (int p = 0; p < 2; p++) {
        int kv = p * 32 + (t >> 3), c0 = (t & 7) * 8;
        u32x4 v = *(const u32x4*)&src[(size_t)kv * INNER + c0];
        *(u32x4*)&tile[kv][c0] = v;
    }
    __syncthreads();
    ushort* dst = vtb + (((size_t)b * HEADS + h) * DH) * NKV + kt * 64;
#pragma unroll
    for (int p = 0; p < 2; p++) {
        int d = p * 32 + (t >> 3), k0 = (t & 7) * 8;
        ushort tmp[8];
#pragma unroll
        for (int j = 0; j < 8; j++) tmp[j] = tile[k0 + j][d];
        *(u32x4*)&dst[(size_t)d * NKV + k0] = *(u32x4*)tmp;
    }
}

// ---------------- bf16 GEMM: C[M][N] = A[M][K] * Bt[N][K]^T, 128 x BN tile ----------------
// counted-vmcnt pipeline: next-tile staging loads stay in flight across the barrier.
// MODE 0: bf16 out (scaled) ; MODE 1: bf16 split k/v ; MODE 2: f32 out + bias
template <int MODE, int BN>
__global__ __launch_bounds__(256) void gemm_bt(const ushort* __restrict__ A, const ushort* __restrict__ Bt,
                                               void* __restrict__ C0, void* __restrict__ C1,
                                               const float* __restrict__ bias, float oscale,
                                               int M, int N, int K) {
    constexpr int NI = BN / 32;           // n-blocks per wave
    constexpr int NL = (BN == 128) ? 4 : 3;  // staging loads per thread per tile
    __shared__ ushort As[2][4096];        // [kc4][row128][8]
    __shared__ ushort Bs[2][BN * 32];     // [kc4][rowBN][8]
    int m0 = blockIdx.y * 128, n0 = blockIdx.x * BN;
    int t = threadIdx.x, l = t & 63, w = t >> 6;
    int wr = w >> 1, wc = w & 1;
    int lg = l >> 4, lc = l & 15;
    f32x4 acc[4][NI] = {};

    auto stage = [&](int buf, int k0) {
#pragma unroll
        for (int i = 0; i < 2; i++) {
            int s = w + i * 4;
            gload16(A + (size_t)(m0 + (s & 1) * 64 + l) * K + k0 + (s >> 1) * 8, &As[buf][s * 512]);
        }
        if (BN == 128) {
#pragma unroll
            for (int i = 0; i < 2; i++) {
                int s = w + i * 4;
                gload16(Bt + (size_t)(n0 + (s & 1) * 64 + l) * K + k0 + (s >> 1) * 8, &Bs[buf][s * 512]);
            }
        } else {
            gload16(Bt + (size_t)(n0 + l) * K + k0 + w * 8, &Bs[buf][w * 512]);
        }
    };

    stage(0, 0);
    for (int k0 = 0, tt = 0; k0 < K; k0 += 32, ++tt) {
        int cur = tt & 1;
        if (k0 + 32 < K) {
            stage(cur ^ 1, k0 + 32);   // issue next tile, leave in flight
            asm volatile("s_waitcnt vmcnt(%0)" :: "n"(NL) : "memory");  // own cur-tile loads done
        } else {
            asm volatile("s_waitcnt vmcnt(0)" ::: "memory");
        }
        __builtin_amdgcn_s_barrier();
        asm volatile("" ::: "memory");
        bf16x8 af[4], bf[NI];
#pragma unroll
        for (int mi = 0; mi < 4; mi++)
            af[mi] = *(const bf16x8*)&As[cur][(lg * 128 + wr * 64 + mi * 16 + lc) * 8];
#pragma unroll
        for (int ni = 0; ni < NI; ni++)
            bf[ni] = *(const bf16x8*)&Bs[cur][(lg * BN + wc * (BN / 2) + ni * 16 + lc) * 8];
        __builtin_amdgcn_s_setprio(1);
#pragma unroll
        for (int mi = 0; mi < 4; mi++)
#pragma unroll
            for (int ni = 0; ni < NI; ni++)
                acc[mi][ni] = __builtin_amdgcn_mfma_f32_16x16x32_bf16(af[mi], bf[ni], acc[mi][ni], 0, 0, 0);
        __builtin_amdgcn_s_setprio(0);
        asm volatile("s_waitcnt lgkmcnt(0)" ::: "memory");   // all own LDS reads done
        __builtin_amdgcn_s_barrier();                        // before next stage overwrites
        asm volatile("" ::: "memory");
    }
#pragma unroll
    for (int mi = 0; mi < 4; mi++)
#pragma unroll
        for (int ni = 0; ni < NI; ni++)
#pragma unroll
            for (int r = 0; r < 4; r++) {
                int m = m0 + wr * 64 + mi * 16 + lg * 4 + r;
                int n = n0 + wc * (BN / 2) + ni * 16 + lc;
                float v = acc[mi][ni][r];
                if (MODE == 0) {
                    ((ushort*)C0)[(size_t)m * N + n] = f2b(v * oscale);
                } else if (MODE == 1) {
                    if (n < 1024) ((ushort*)C0)[(size_t)m * 1024 + n] = f2b(v);
                    else          ((ushort*)C1)[(size_t)m * 1024 + (n - 1024)] = f2b(v);
                } else {
                    ((float*)C0)[(size_t)m * N + n] = v + bias[n];
                }
            }
}

// ---------------- flash attention v6: QBLK=64, 2 waves x 32 q, KVBLK=64 dbuf ----------------
// swapped QK^T, in-reg softmax (exp2), P aliases Q-LDS. qb pre-scaled 0.125*log2e. vtb [b][h][d][kv].
__global__ __launch_bounds__(128, 2) void attn3(const ushort* __restrict__ qb, const ushort* __restrict__ kb,
                                                const ushort* __restrict__ vtb, ushort* __restrict__ ob) {
    __shared__ ushort Qs[8 * 64 * 8];    // [dc8][q64][8]  8KB; reused as P (2 waves x 4KB)
    __shared__ ushort Ks[2][4096];       // [dc8][kv64][8] 16KB
    __shared__ ushort Vs[2][4096];       // [kvc8][d64][8] 16KB
    int flat = blockIdx.x;
    int swz = (flat & 7) * 128 + (flat >> 3);          // XCD-chunked (1024 % 8 == 0)
    int qt = swz & 31, h = (swz >> 5) & 15, b = swz >> 9;
    int t = threadIdx.x, l = t & 63, w = t >> 6;       // w in {0,1}
    int lg = l >> 4, lc = l & 15;
    int xsw = (lc << 1) & 0x1C;
    const ushort* Qg = qb + (size_t)b * NQ * INNER + h * DH;
    const ushort* Kg = kb + (size_t)b * NKV * INNER + h * DH;
    const ushort* Vg = vtb + (((size_t)b * HEADS + h) * DH) * NKV;
    int q0 = qt * 64;

    // stage Q (8 segments of 1KB; wave w does s = w*4 .. w*4+3)
#pragma unroll
    for (int i = 0; i < 4; i++) {
        int s = w * 4 + i;
        gload16(Qg + (size_t)(q0 + l) * INNER + s * 8, &Qs[s * 512]);
    }
    auto stageKV = [&](int buf, int kv0) {
#pragma unroll
        for (int i = 0; i < 4; i++) {
            int s = w * 4 + i;
            gload16(Kg + (size_t)(kv0 + l) * INNER + s * 8, &Ks[buf][s * 512]);
            gload16(Vg + (size_t)l * NKV + kv0 + s * 8, &Vs[buf][s * 512]);
        }
    };
    stageKV(0, 0);
    __syncthreads();

    bf16x8 qf[2][2];   // [mi][kc]: B-frag rows q = w*32 + mi*16 + lc
#pragma unroll
    for (int mi = 0; mi < 2; mi++)
#pragma unroll
        for (int kc = 0; kc < 2; kc++)
            qf[mi][kc] = *(const bf16x8*)&Qs[((kc * 4 + lg) * 64 + w * 32 + mi * 16 + lc) * 8];
    __syncthreads();   // all waves done reading Q before Qs is reused as P

    uint* Ps = (uint*)Qs + w * 1024;     // per-wave [q32][32 pair-words], swizzled (4KB)
    f32x4 o[2][4] = {};                  // O^T: [mi][nb d-block], row d = nb*16+lg*4+r, col q = lc
    float m_[2] = {-1e30f, -1e30f}, s_[2] = {0.f, 0.f};

    for (int tt = 0; tt < NKV / 64; ++tt) {
        int cur = tt & 1;
        if (tt + 1 < NKV / 64) stageKV(cur ^ 1, (tt + 1) * 64);
        // S^T[kv][q] = mfma(A=K rows, B=Q rows), in log2 units
        f32x4 st[2][4] = {};
        __builtin_amdgcn_s_setprio(1);
#pragma unroll
        for (int kc = 0; kc < 2; kc++)
#pragma unroll
            for (int nb = 0; nb < 4; nb++) {
                bf16x8 kf = *(const bf16x8*)&Ks[cur][((kc * 4 + lg) * 64 + nb * 16 + lc) * 8];
                st[0][nb] = __builtin_amdgcn_mfma_f32_16x16x32_bf16(kf, qf[0][kc], st[0][nb], 0, 0, 0);
                st[1][nb] = __builtin_amdgcn_mfma_f32_16x16x32_bf16(kf, qf[1][kc], st[1][nb], 0, 0, 0);
            }
        __builtin_amdgcn_s_setprio(0);
        // per-mi in-register online softmax (lane owns q = mi*16+lc; kv = nb*16+lg*4+r)
#pragma unroll
        for (int mi = 0; mi < 2; mi++) {
            float mx = st[mi][0][0];
#pragma unroll
            for (int nb = 0; nb < 4; nb++)
#pragma unroll
                for (int r = 0; r < 4; r++) mx = fmaxf(mx, st[mi][nb][r]);
            mx = fmaxf(mx, __shfl_xor(mx, 16));
            mx = fmaxf(mx, __shfl_xor(mx, 32));
            float mn = fmaxf(m_[mi], mx);
            float fac = __builtin_amdgcn_exp2f(m_[mi] - mn);
            m_[mi] = mn;
            s_[mi] *= fac;
#pragma unroll
            for (int nb = 0; nb < 4; nb++) o[mi][nb] *= fac;
            float rs = 0.f;
#pragma unroll
            for (int nb = 0; nb < 4; nb++) {
                float p0 = __builtin_amdgcn_exp2f(st[mi][nb][0] - mn);
                float p1 = __builtin_amdgcn_exp2f(st[mi][nb][1] - mn);
                float p2 = __builtin_amdgcn_exp2f(st[mi][nb][2] - mn);
                float p3 = __builtin_amdgcn_exp2f(st[mi][nb][3] - mn);
                rs += (p0 + p1) + (p2 + p3);
                uint2 pw;
                pw.x = pkbf16(p0, p1);
                pw.y = pkbf16(p2, p3);
                *(uint2*)&Ps[(mi * 16 + lc) * 32 + ((nb * 8 + lg * 2) ^ xsw)] = pw;
            }
            rs += __shfl_xor(rs, 16);
            rs += __shfl_xor(rs, 32);
            s_[mi] += rs;
        }
        // compiler-level memory fence: forbid hoisting the P reads above the P writes
        asm volatile("" ::: "memory");
        // PV: O^T[d][q] += mfma(A=V^T rows d, B=P rows q)
        bf16x8 pf[2][2], vf[4][2];
#pragma unroll
        for (int mi = 0; mi < 2; mi++)
#pragma unroll
            for (int kc = 0; kc < 2; kc++)
                pf[mi][kc] = *(const bf16x8*)&Ps[(mi * 16 + lc) * 32 + ((kc * 16 + lg * 4) ^ xsw)];
#pragma unroll
        for (int nb = 0; nb < 4; nb++)
#pragma unroll
            for (int kc = 0; kc < 2; kc++)
                vf[nb][kc] = *(const bf16x8*)&Vs[cur][((kc * 4 + lg) * 64 + nb * 16 + lc) * 8];
        __builtin_amdgcn_s_setprio(1);
#pragma unroll
        for (int nb = 0; nb < 4; nb++)
#pragma unroll
            for (int kc = 0; kc < 2; kc++) {
                o[0][nb] = __builtin_amdgcn_mfma_f32_16x16x32_bf16(vf[nb][kc], pf[0][kc], o[0][nb], 0, 0, 0);
                o[1][nb] = __builtin_amdgcn_mfma_f32_16x16x32_bf16(vf[nb][kc], pf[1][kc], o[1][nb], 0, 0, 0);
            }
        __builtin_amdgcn_s_setprio(0);
        __syncthreads();
    }
    ushort* Og = ob + (size_t)b * NQ * INNER + h * DH;
#pragma unroll
    for (int mi = 0; mi < 2; mi++) {
        float inv = 1.f / s_[mi];
        int q = q0 + w * 32 + mi * 16 + lc;
#pragma unroll
        for (int nb = 0; nb < 4; nb++) {
            uint2 pw;
            pw.x = pkbf16(o[mi][nb][0] * inv, o[mi][nb][1] * inv);
            pw.y = pkbf16(o[mi][nb][2] * inv, o[mi][nb][3] * inv);
            *(uint2*)&Og[(size_t)q * INNER + nb * 16 + lg * 4] = pw;
        }
    }
}

extern "C" void kernel_launch(void* const* d_in, const int* in_sizes, int n_in,
                              void* d_out, int out_size, void* d_ws, size_t ws_size,
                              hipStream_t stream) {
    const float* x    = (const float*)d_in[0];
    const float* ctx  = (const float*)d_in[1];
    const float* Wq   = (const float*)d_in[2];
    const float* Wkv  = (const float*)d_in[3];
    const float* Wout = (const float*)d_in[4];
    const float* bout = (const float*)d_in[5];
    float* out = (float*)d_out;

    if (ws_size < (size_t)(56u << 20)) return;  // need 56MB scratch
    char* ws = (char*)d_ws;
    ushort* xb    = (ushort*)(ws);                 // 8MB, dead after q-gemm
    ushort* vtb   = (ushort*)(ws);                 // reuse xb slot
    ushort* cb    = (ushort*)(ws + (8u << 20));    // 8MB, dead after kv-gemm
    ushort* ob    = (ushort*)(ws + (8u << 20));    // reuse cb slot
    ushort* qb    = (ushort*)(ws + (16u << 20));
    ushort* kb    = (ushort*)(ws + (24u << 20));
    ushort* vb    = (ushort*)(ws + (32u << 20));
    ushort* Wqt   = (ushort*)(ws + (48u << 20));
    ushort* Wkvt  = (ushort*)(ws + (50u << 20));
    ushort* Woutt = (ushort*)(ws + (54u << 20));

    cvt2<<<2048, 256, 0, stream>>>(x, xb, ctx, cb, (BATCH * NQ * DIM) / 4);
    transp4<<<dim3(32, 32, 4), dim3(32, 8), 0, stream>>>(Wq, Wkv, Wout, Wqt, Wkvt, Woutt);

    // q-proj scaled by 0.125 * log2(e) so attention logits are in exp2 units
    gemm_bt<0, 64><<<dim3(16, 32), 256, 0, stream>>>(xb, Wqt, qb, nullptr, nullptr, 0.125f * 1.44269504f, 4096, 1024, 1024);
    gemm_bt<1, 128><<<dim3(16, 32), 256, 0, stream>>>(cb, Wkvt, kb, vb, nullptr, 1.f, 4096, 2048, 1024);
    vtransp<<<dim3(32, 16, 2), 256, 0, stream>>>(vb, vtb);
    attn3<<<1024, 128, 0, stream>>>(qb, kb, vtb, ob);
    gemm_bt<2, 64><<<dim3(16, 32), 256, 0, stream>>>(ob, Woutt, out, nullptr, bout, 1.f, 4096, 1024, 1024);
}

// Round 10
// 193.053 us; speedup vs baseline: 1.0222x; 1.0222x over previous
//
#include <hip/hip_runtime.h>
#include <hip/hip_bf16.h>
#include <stdint.h>

#define NQ 2048
#define NKV 2048
#define DIM 1024
#define INNER 1024
#define HEADS 16
#define DH 64
#define BATCH 2

typedef float f32x4 __attribute__((ext_vector_type(4)));
typedef __bf16 bf16x8 __attribute__((ext_vector_type(8)));
typedef unsigned int u32x4 __attribute__((ext_vector_type(4)));

__device__ inline ushort f2b(float f) {
    uint32_t u = __builtin_bit_cast(uint32_t, f);
    u += 0x7fff + ((u >> 16) & 1);   // round-to-nearest-even
    return (ushort)(u >> 16);
}

__device__ inline uint pkbf16(float lo, float hi) {
    __hip_bfloat162 h = __float22bfloat162_rn(make_float2(lo, hi));
    uint r;
    __builtin_memcpy(&r, &h, 4);   // low 16 = bf16(lo), high 16 = bf16(hi)
    return r;
}

__device__ __forceinline__ void gload16(const void* g, void* lds) {
    __builtin_amdgcn_global_load_lds(
        (const __attribute__((address_space(1))) unsigned int*)g,
        (__attribute__((address_space(3))) unsigned int*)lds, 16, 0, 0);
}

// ---------------- fused prep: z<4 -> weight transpose+cvt slices; z==4 -> x/ctx convert ----------------
__global__ void prep(const float* __restrict__ x, const float* __restrict__ ctx,
                     const float* __restrict__ Wq, const float* __restrict__ Wkv,
                     const float* __restrict__ Wout,
                     ushort* __restrict__ xb, ushort* __restrict__ cb,
                     ushort* __restrict__ Wqt, ushort* __restrict__ Wkvt,
                     ushort* __restrict__ Woutt) {
    int z = blockIdx.z;
    if (z < 4) {
        __shared__ ushort tile[32][33];
        const float* src; ushort* dst; int C;
        if (z == 0)      { src = Wq;          dst = Wqt;                C = 1024; }
        else if (z == 1) { src = Wkv;         dst = Wkvt;               C = 2048; }
        else if (z == 2) { src = Wkv + 1024;  dst = Wkvt + 1024 * 1024; C = 2048; }
        else             { src = Wout;        dst = Woutt;              C = 1024; }
        int c0 = blockIdx.x * 32, r0 = blockIdx.y * 32;
        int tx = threadIdx.x, ty = threadIdx.y;   // 32 x 8
#pragma unroll
        for (int i = 0; i < 4; i++)
            tile[ty + i * 8][tx] = f2b(src[(size_t)(r0 + ty + i * 8) * C + c0 + tx]);
        __syncthreads();
#pragma unroll
        for (int i = 0; i < 4; i++)
            dst[(size_t)(c0 + ty + i * 8) * 1024 + r0 + tx] = tile[tx][ty + i * 8];
    } else {
        const int n4 = (BATCH * NQ * DIM) / 4;   // float4 count per tensor
        int fb = blockIdx.y * 32 + blockIdx.x;   // 0..1023
        int t = threadIdx.y * 32 + threadIdx.x;  // 0..255
        for (int i = fb * 256 + t; i < 2 * n4; i += 1024 * 256) {
            float4 v;
            if (i < n4) v = ((const float4*)x)[i];
            else        v = ((const float4*)ctx)[i - n4];
            ushort4 o;
            o.x = f2b(v.x); o.y = f2b(v.y); o.z = f2b(v.z); o.w = f2b(v.w);
            if (i < n4) ((ushort4*)xb)[i] = o;
            else        ((ushort4*)cb)[i - n4] = o;
        }
    }
}

// ---------------- fused q-proj + kv-proj GEMM: 768 blocks of 128x128, K=1024 ----------------
// blocks 0..255: qb = xb @ Wqt^T * qscale (bf16)
// blocks 256..767: kv = cb @ Wkvt^T; n<1024 -> kb row-major; n>=1024 -> vtb[b][h][d][kv] (transposed)
__global__ __launch_bounds__(256) void gemm_qkv(const ushort* __restrict__ xb, const ushort* __restrict__ cb,
                                                const ushort* __restrict__ Wqt, const ushort* __restrict__ Wkvt,
                                                ushort* __restrict__ qb, ushort* __restrict__ kb,
                                                ushort* __restrict__ vtb, float qscale) {
    constexpr int K = 1024;
    __shared__ ushort As[2][4096];        // [kc4][row128][8]
    __shared__ ushort Bs[2][4096];
    int bid = blockIdx.x;
    bool isq = bid < 256;
    const ushort *A, *Bt;
    int m0, n0;
    if (isq) { A = xb; Bt = Wqt;  m0 = (bid >> 3) * 128; n0 = (bid & 7) * 128; }
    else     { int b2 = bid - 256; A = cb; Bt = Wkvt; m0 = (b2 >> 4) * 128; n0 = (b2 & 15) * 128; }
    int t = threadIdx.x, l = t & 63, w = t >> 6;
    int wr = w >> 1, wc = w & 1;
    int lg = l >> 4, lc = l & 15;
    f32x4 acc[4][4] = {};

    auto stage = [&](int buf, int k0) {
#pragma unroll
        for (int i = 0; i < 2; i++) {
            int s = w + i * 4;
            gload16(A + (size_t)(m0 + (s & 1) * 64 + l) * K + k0 + (s >> 1) * 8, &As[buf][s * 512]);
            gload16(Bt + (size_t)(n0 + (s & 1) * 64 + l) * K + k0 + (s >> 1) * 8, &Bs[buf][s * 512]);
        }
    };

    stage(0, 0);
    for (int k0 = 0, tt = 0; k0 < K; k0 += 32, ++tt) {
        int cur = tt & 1;
        if (k0 + 32 < K) {
            stage(cur ^ 1, k0 + 32);   // issue next tile, leave in flight
            asm volatile("s_waitcnt vmcnt(4)" ::: "memory");   // own cur-tile loads done
        } else {
            asm volatile("s_waitcnt vmcnt(0)" ::: "memory");
        }
        __builtin_amdgcn_s_barrier();
        asm volatile("" ::: "memory");
        bf16x8 af[4], bf[4];
#pragma unroll
        for (int mi = 0; mi < 4; mi++)
            af[mi] = *(const bf16x8*)&As[cur][(lg * 128 + wr * 64 + mi * 16 + lc) * 8];
#pragma unroll
        for (int ni = 0; ni < 4; ni++)
            bf[ni] = *(const bf16x8*)&Bs[cur][(lg * 128 + wc * 64 + ni * 16 + lc) * 8];
        __builtin_amdgcn_s_setprio(1);
#pragma unroll
        for (int mi = 0; mi < 4; mi++)
#pragma unroll
            for (int ni = 0; ni < 4; ni++)
                acc[mi][ni] = __builtin_amdgcn_mfma_f32_16x16x32_bf16(af[mi], bf[ni], acc[mi][ni], 0, 0, 0);
        __builtin_amdgcn_s_setprio(0);
        asm volatile("s_waitcnt lgkmcnt(0)" ::: "memory");
        __builtin_amdgcn_s_barrier();
        asm volatile("" ::: "memory");
    }
    if (isq) {
#pragma unroll
        for (int mi = 0; mi < 4; mi++)
#pragma unroll
            for (int ni = 0; ni < 4; ni++)
#pragma unroll
                for (int r = 0; r < 4; r++) {
                    int m = m0 + wr * 64 + mi * 16 + lg * 4 + r;
                    int n = n0 + wc * 64 + ni * 16 + lc;
                    qb[(size_t)m * 1024 + n] = f2b(acc[mi][ni][r] * qscale);
                }
    } else if (n0 < 1024) {      // k half: row-major (block-uniform)
#pragma unroll
        for (int mi = 0; mi < 4; mi++)
#pragma unroll
            for (int ni = 0; ni < 4; ni++)
#pragma unroll
                for (int r = 0; r < 4; r++) {
                    int m = m0 + wr * 64 + mi * 16 + lg * 4 + r;
                    int n = n0 + wc * 64 + ni * 16 + lc;
                    kb[(size_t)m * 1024 + n] = f2b(acc[mi][ni][r]);
                }
    } else {                     // v half: write transposed vtb[b][h][d][kv]
#pragma unroll
        for (int mi = 0; mi < 4; mi++)
#pragma unroll
            for (int ni = 0; ni < 4; ni++) {
                int n = n0 - 1024 + wc * 64 + ni * 16 + lc;   // 0..1023
                int h = n >> 6, d = n & 63;
                int mrow = m0 + wr * 64 + mi * 16 + lg * 4;
                int b = mrow >> 11, kv = mrow & 2047;
                ushort4 pk;
                pk.x = f2b(acc[mi][ni][0]); pk.y = f2b(acc[mi][ni][1]);
                pk.z = f2b(acc[mi][ni][2]); pk.w = f2b(acc[mi][ni][3]);
                *(ushort4*)&vtb[(((size_t)b * HEADS + h) * DH + d) * (size_t)NKV + kv] = pk;
            }
    }
}

// ---------------- out-proj GEMM: C[M][N] = A[M][K] * Bt[N][K]^T, 128 x 64 tile, f32 out + bias ----------------
__global__ __launch_bounds__(256) void gemm_out(const ushort* __restrict__ A, const ushort* __restrict__ Bt,
                                                float* __restrict__ C0, const float* __restrict__ bias,
                                                int M, int N, int K) {
    __shared__ ushort As[2][4096];        // [kc4][row128][8]
    __shared__ ushort Bs[2][2048];        // [kc4][row64][8]
    int m0 = blockIdx.y * 128, n0 = blockIdx.x * 64;
    int t = threadIdx.x, l = t & 63, w = t >> 6;
    int wr = w >> 1, wc = w & 1;
    int lg = l >> 4, lc = l & 15;
    f32x4 acc[4][2] = {};

    auto stage = [&](int buf, int k0) {
#pragma unroll
        for (int i = 0; i < 2; i++) {
            int s = w + i * 4;
            gload16(A + (size_t)(m0 + (s & 1) * 64 + l) * K + k0 + (s >> 1) * 8, &As[buf][s * 512]);
        }
        gload16(Bt + (size_t)(n0 + l) * K + k0 + w * 8, &Bs[buf][w * 512]);
    };

    stage(0, 0);
    for (int k0 = 0, tt = 0; k0 < K; k0 += 32, ++tt) {
        int cur = tt & 1;
        if (k0 + 32 < K) {
            stage(cur ^ 1, k0 + 32);
            asm volatile("s_waitcnt vmcnt(3)" ::: "memory");
        } else {
            asm volatile("s_waitcnt vmcnt(0)" ::: "memory");
        }
        __builtin_amdgcn_s_barrier();
        asm volatile("" ::: "memory");
        bf16x8 af[4], bf[2];
#pragma unroll
        for (int mi = 0; mi < 4; mi++)
            af[mi] = *(const bf16x8*)&As[cur][(lg * 128 + wr * 64 + mi * 16 + lc) * 8];
#pragma unroll
        for (int ni = 0; ni < 2; ni++)
            bf[ni] = *(const bf16x8*)&Bs[cur][(lg * 64 + wc * 32 + ni * 16 + lc) * 8];
        __builtin_amdgcn_s_setprio(1);
#pragma unroll
        for (int mi = 0; mi < 4; mi++)
#pragma unroll
            for (int ni = 0; ni < 2; ni++)
                acc[mi][ni] = __builtin_amdgcn_mfma_f32_16x16x32_bf16(af[mi], bf[ni], acc[mi][ni], 0, 0, 0);
        __builtin_amdgcn_s_setprio(0);
        asm volatile("s_waitcnt lgkmcnt(0)" ::: "memory");
        __builtin_amdgcn_s_barrier();
        asm volatile("" ::: "memory");
    }
#pragma unroll
    for (int mi = 0; mi < 4; mi++)
#pragma unroll
        for (int ni = 0; ni < 2; ni++)
#pragma unroll
            for (int r = 0; r < 4; r++) {
                int m = m0 + wr * 64 + mi * 16 + lg * 4 + r;
                int n = n0 + wc * 32 + ni * 16 + lc;
                C0[(size_t)m * N + n] = acc[mi][ni][r] + bias[n];
            }
}

// ---------------- flash attention (R7 structure): QBLK=128 (4 waves x 32 q), KVBLK=64 dbuf ----------------
// swapped QK^T, in-reg softmax (exp2) + defer-max, P aliases Q-LDS. qb pre-scaled 0.125*log2e.
__global__ __launch_bounds__(256, 3) void attn3(const ushort* __restrict__ qb, const ushort* __restrict__ kb,
                                                const ushort* __restrict__ vtb, ushort* __restrict__ ob) {
    __shared__ ushort Qs[8 * 128 * 8];   // [dc8][q128][8] 16KB; reused as P after Q consumed
    __shared__ ushort Ks[2][4096];       // [dc8][kv64][8]    16KB
    __shared__ ushort Vs[2][4096];       // [kvc8][d64][8]    16KB
    int flat = blockIdx.x;
    int swz = (flat & 7) * 64 + (flat >> 3);           // XCD-chunked (512 % 8 == 0)
    int qt = swz & 15, h = (swz >> 4) & 15, b = swz >> 8;
    int t = threadIdx.x, l = t & 63, w = t >> 6;
    int lg = l >> 4, lc = l & 15;
    int xsw = (lc << 1) & 0x1C;
    const ushort* Qg = qb + (size_t)b * NQ * INNER + h * DH;
    const ushort* Kg = kb + (size_t)b * NKV * INNER + h * DH;
    const ushort* Vg = vtb + (((size_t)b * HEADS + h) * DH) * NKV;
    int q0 = qt * 128;

    // stage Q (16 segments of 1KB)
#pragma unroll
    for (int i = 0; i < 4; i++) {
        int s = w * 4 + i;
        gload16(Qg + (size_t)(q0 + (s & 1) * 64 + l) * INNER + (s >> 1) * 8, &Qs[s * 512]);
    }
    auto stageKV = [&](int buf, int kv0) {
#pragma unroll
        for (int i = 0; i < 2; i++) {
            int s = w + i * 4;
            gload16(Kg + (size_t)(kv0 + l) * INNER + s * 8, &Ks[buf][s * 512]);
            gload16(Vg + (size_t)l * NKV + kv0 + s * 8, &Vs[buf][s * 512]);
        }
    };
    stageKV(0, 0);
    __syncthreads();

    bf16x8 qf[2][2];   // [mi][kc]: B-frag rows q = w*32 + mi*16 + lc
#pragma unroll
    for (int mi = 0; mi < 2; mi++)
#pragma unroll
        for (int kc = 0; kc < 2; kc++)
            qf[mi][kc] = *(const bf16x8*)&Qs[((kc * 4 + lg) * 128 + w * 32 + mi * 16 + lc) * 8];
    __syncthreads();   // all waves done reading Q before Qs is reused as P

    uint* Ps = (uint*)Qs + w * 1024;     // per-wave [q32][32 pair-words], swizzled (4KB)
    f32x4 o[2][4] = {};                  // O^T: [mi][nb d-block], row d = nb*16+lg*4+r, col q = lc
    float m_[2] = {-1e30f, -1e30f}, s_[2] = {0.f, 0.f};

    for (int tt = 0; tt < NKV / 64; ++tt) {
        int cur = tt & 1;
        if (tt + 1 < NKV / 64) stageKV(cur ^ 1, (tt + 1) * 64);
        // S^T[kv][q] = mfma(A=K rows, B=Q rows), in log2 units
        f32x4 st[2][4] = {};
        __builtin_amdgcn_s_setprio(1);
#pragma unroll
        for (int kc = 0; kc < 2; kc++)
#pragma unroll
            for (int nb = 0; nb < 4; nb++) {
                bf16x8 kf = *(const bf16x8*)&Ks[cur][((kc * 4 + lg) * 64 + nb * 16 + lc) * 8];
                st[0][nb] = __builtin_amdgcn_mfma_f32_16x16x32_bf16(kf, qf[0][kc], st[0][nb], 0, 0, 0);
                st[1][nb] = __builtin_amdgcn_mfma_f32_16x16x32_bf16(kf, qf[1][kc], st[1][nb], 0, 0, 0);
            }
        __builtin_amdgcn_s_setprio(0);
        // per-mi in-register online softmax (lane owns q = mi*16+lc; kv = nb*16+lg*4+r)
#pragma unroll
        for (int mi = 0; mi < 2; mi++) {
            float mx = st[mi][0][0];
#pragma unroll
            for (int nb = 0; nb < 4; nb++)
#pragma unroll
                for (int r = 0; r < 4; r++) mx = fmaxf(mx, st[mi][nb][r]);
            mx = fmaxf(mx, __shfl_xor(mx, 16));
            mx = fmaxf(mx, __shfl_xor(mx, 32));
            if (!__all(mx - m_[mi] <= 8.f)) {    // defer-max (T13): rescale only on real growth
                float mn = fmaxf(m_[mi], mx);
                float fac = __builtin_amdgcn_exp2f(m_[mi] - mn);
                m_[mi] = mn;
                s_[mi] *= fac;
#pragma unroll
                for (int nb = 0; nb < 4; nb++) o[mi][nb] *= fac;
            }
            float mn = m_[mi];
            float rs = 0.f;
#pragma unroll
            for (int nb = 0; nb < 4; nb++) {
                float p0 = __builtin_amdgcn_exp2f(st[mi][nb][0] - mn);
                float p1 = __builtin_amdgcn_exp2f(st[mi][nb][1] - mn);
                float p2 = __builtin_amdgcn_exp2f(st[mi][nb][2] - mn);
                float p3 = __builtin_amdgcn_exp2f(st[mi][nb][3] - mn);
                rs += (p0 + p1) + (p2 + p3);
                uint2 pw;
                pw.x = pkbf16(p0, p1);
                pw.y = pkbf16(p2, p3);
                *(uint2*)&Ps[(mi * 16 + lc) * 32 + ((nb * 8 + lg * 2) ^ xsw)] = pw;
            }
            rs += __shfl_xor(rs, 16);
            rs += __shfl_xor(rs, 32);
            s_[mi] += rs;
        }
        // compiler-level memory fence: forbid hoisting the P reads above the P writes
        asm volatile("" ::: "memory");
        // PV: O^T[d][q] += mfma(A=V^T rows d, B=P rows q)
        bf16x8 pf[2][2], vf[4][2];
#pragma unroll
        for (int mi = 0; mi < 2; mi++)
#pragma unroll
            for (int kc = 0; kc < 2; kc++)
                pf[mi][kc] = *(const bf16x8*)&Ps[(mi * 16 + lc) * 32 + ((kc * 16 + lg * 4) ^ xsw)];
#pragma unroll
        for (int nb = 0; nb < 4; nb++)
#pragma unroll
            for (int kc = 0; kc < 2; kc++)
                vf[nb][kc] = *(const bf16x8*)&Vs[cur][((kc * 4 + lg) * 64 + nb * 16 + lc) * 8];
        __builtin_amdgcn_s_setprio(1);
#pragma unroll
        for (int nb = 0; nb < 4; nb++)
#pragma unroll
            for (int kc = 0; kc < 2; kc++) {
                o[0][nb] = __builtin_amdgcn_mfma_f32_16x16x32_bf16(vf[nb][kc], pf[0][kc], o[0][nb], 0, 0, 0);
                o[1][nb] = __builtin_amdgcn_mfma_f32_16x16x32_bf16(vf[nb][kc], pf[1][kc], o[1][nb], 0, 0, 0);
            }
        __builtin_amdgcn_s_setprio(0);
        __syncthreads();
    }
    ushort* Og = ob + (size_t)b * NQ * INNER + h * DH;
#pragma unroll
    for (int mi = 0; mi < 2; mi++) {
        float inv = 1.f / s_[mi];
        int q = q0 + w * 32 + mi * 16 + lc;
#pragma unroll
        for (int nb = 0; nb < 4; nb++) {
            uint2 pw;
            pw.x = pkbf16(o[mi][nb][0] * inv, o[mi][nb][1] * inv);
            pw.y = pkbf16(o[mi][nb][2] * inv, o[mi][nb][3] * inv);
            *(uint2*)&Og[(size_t)q * INNER + nb * 16 + lg * 4] = pw;
        }
    }
}

extern "C" void kernel_launch(void* const* d_in, const int* in_sizes, int n_in,
                              void* d_out, int out_size, void* d_ws, size_t ws_size,
                              hipStream_t stream) {
    const float* x    = (const float*)d_in[0];
    const float* ctx  = (const float*)d_in[1];
    const float* Wq   = (const float*)d_in[2];
    const float* Wkv  = (const float*)d_in[3];
    const float* Wout = (const float*)d_in[4];
    const float* bout = (const float*)d_in[5];
    float* out = (float*)d_out;

    if (ws_size < (size_t)(56u << 20)) return;  // need 56MB scratch
    char* ws = (char*)d_ws;
    ushort* xb    = (ushort*)(ws);                 // 8MB
    ushort* cb    = (ushort*)(ws + (8u << 20));    // 8MB, dead after gemm_qkv
    ushort* ob    = (ushort*)(ws + (8u << 20));    // reuse cb slot
    ushort* qb    = (ushort*)(ws + (16u << 20));
    ushort* kb    = (ushort*)(ws + (24u << 20));
    ushort* vtb   = (ushort*)(ws + (32u << 20));   // old vb slot (v goes straight to transposed)
    ushort* Wqt   = (ushort*)(ws + (48u << 20));
    ushort* Wkvt  = (ushort*)(ws + (50u << 20));
    ushort* Woutt = (ushort*)(ws + (54u << 20));

    prep<<<dim3(32, 32, 5), dim3(32, 8), 0, stream>>>(x, ctx, Wq, Wkv, Wout, xb, cb, Wqt, Wkvt, Woutt);
    // fused q-proj (scaled by 0.125*log2e) + kv-proj (v written transposed)
    gemm_qkv<<<768, 256, 0, stream>>>(xb, cb, Wqt, Wkvt, qb, kb, vtb, 0.125f * 1.44269504f);
    attn3<<<512, 256, 0, stream>>>(qb, kb, vtb, ob);
    gemm_out<<<dim3(16, 32), 256, 0, stream>>>(ob, Woutt, out, bout, 4096, 1024, 1024);
}

// Round 11
// 193.007 us; speedup vs baseline: 1.0225x; 1.0002x over previous
//
#include <hip/hip_runtime.h>
#include <hip/hip_bf16.h>
#include <stdint.h>

#define NQ 2048
#define NKV 2048
#define DIM 1024
#define INNER 1024
#define HEADS 16
#define DH 64
#define BATCH 2

typedef float f32x4 __attribute__((ext_vector_type(4)));
typedef __bf16 bf16x8 __attribute__((ext_vector_type(8)));
typedef unsigned int u32x4 __attribute__((ext_vector_type(4)));

__device__ inline ushort f2b(float f) {
    uint32_t u = __builtin_bit_cast(uint32_t, f);
    u += 0x7fff + ((u >> 16) & 1);   // round-to-nearest-even
    return (ushort)(u >> 16);
}

__device__ inline uint pkbf16(float lo, float hi) {
    __hip_bfloat162 h = __float22bfloat162_rn(make_float2(lo, hi));
    uint r;
    __builtin_memcpy(&r, &h, 4);   // low 16 = bf16(lo), high 16 = bf16(hi)
    return r;
}

__device__ __forceinline__ void gload16(const void* g, void* lds) {
    __builtin_amdgcn_global_load_lds(
        (const __attribute__((address_space(1))) unsigned int*)g,
        (__attribute__((address_space(3))) unsigned int*)lds, 16, 0, 0);
}

// ---------------- fused prep: z<4 -> weight transpose+cvt slices; z==4 -> x/ctx convert ----------------
__global__ void prep(const float* __restrict__ x, const float* __restrict__ ctx,
                     const float* __restrict__ Wq, const float* __restrict__ Wkv,
                     const float* __restrict__ Wout,
                     ushort* __restrict__ xb, ushort* __restrict__ cb,
                     ushort* __restrict__ Wqt, ushort* __restrict__ Wkvt,
                     ushort* __restrict__ Woutt) {
    int z = blockIdx.z;
    if (z < 4) {
        __shared__ ushort tile[32][33];
        const float* src; ushort* dst; int C;
        if (z == 0)      { src = Wq;          dst = Wqt;                C = 1024; }
        else if (z == 1) { src = Wkv;         dst = Wkvt;               C = 2048; }
        else if (z == 2) { src = Wkv + 1024;  dst = Wkvt + 1024 * 1024; C = 2048; }
        else             { src = Wout;        dst = Woutt;              C = 1024; }
        int c0 = blockIdx.x * 32, r0 = blockIdx.y * 32;
        int tx = threadIdx.x, ty = threadIdx.y;   // 32 x 8
#pragma unroll
        for (int i = 0; i < 4; i++)
            tile[ty + i * 8][tx] = f2b(src[(size_t)(r0 + ty + i * 8) * C + c0 + tx]);
        __syncthreads();
#pragma unroll
        for (int i = 0; i < 4; i++)
            dst[(size_t)(c0 + ty + i * 8) * 1024 + r0 + tx] = tile[tx][ty + i * 8];
    } else {
        const int n4 = (BATCH * NQ * DIM) / 4;   // float4 count per tensor
        int fb = blockIdx.y * 32 + blockIdx.x;   // 0..1023
        int t = threadIdx.y * 32 + threadIdx.x;  // 0..255
        for (int i = fb * 256 + t; i < 2 * n4; i += 1024 * 256) {
            float4 v;
            if (i < n4) v = ((const float4*)x)[i];
            else        v = ((const float4*)ctx)[i - n4];
            ushort4 o;
            o.x = f2b(v.x); o.y = f2b(v.y); o.z = f2b(v.z); o.w = f2b(v.w);
            if (i < n4) ((ushort4*)xb)[i] = o;
            else        ((ushort4*)cb)[i - n4] = o;
        }
    }
}

// ---------------- fused q-proj + kv-proj GEMM: 1536 blocks of 128x64, K=1024 ----------------
// swz < 512: qb = xb @ Wqt^T * qscale
// swz >= 512: kv = cb @ Wkvt^T; n<1024 -> kb row-major; n>=1024 -> vtb[b][h][d][kv] via LDS transpose
__global__ __launch_bounds__(256) void gemm_qkv(const ushort* __restrict__ xb, const ushort* __restrict__ cb,
                                                const ushort* __restrict__ Wqt, const ushort* __restrict__ Wkvt,
                                                ushort* __restrict__ qb, ushort* __restrict__ kb,
                                                ushort* __restrict__ vtb, float qscale) {
    constexpr int K = 1024;
    __shared__ ushort lds[12288];   // As: [2][4096] @0 ; Bs: [2][2048] @8192 ; v-epilogue tile [64][136] @0
    int flat = blockIdx.x;
    int swz = (flat & 7) * 192 + (flat >> 3);     // XCD-chunked, bijective (1536 % 8 == 0)
    bool isq = swz < 512;
    const ushort *A, *Bt;
    int m0, n0;
    if (isq) { A = xb; Bt = Wqt;  m0 = (swz >> 4) * 128;  n0 = (swz & 15) * 64; }
    else     { int b2 = swz - 512; A = cb; Bt = Wkvt; m0 = (b2 >> 5) * 128; n0 = (b2 & 31) * 64; }
    int t = threadIdx.x, l = t & 63, w = t >> 6;
    int wr = w >> 1, wc = w & 1;
    int lg = l >> 4, lc = l & 15;
    f32x4 acc[4][2] = {};

    auto stage = [&](int buf, int k0) {
#pragma unroll
        for (int i = 0; i < 2; i++) {
            int s = w + i * 4;
            gload16(A + (size_t)(m0 + (s & 1) * 64 + l) * K + k0 + (s >> 1) * 8, &lds[buf * 4096 + s * 512]);
        }
        gload16(Bt + (size_t)(n0 + l) * K + k0 + w * 8, &lds[8192 + buf * 2048 + w * 512]);
    };

    stage(0, 0);
    for (int k0 = 0, tt = 0; k0 < K; k0 += 32, ++tt) {
        int cur = tt & 1;
        if (k0 + 32 < K) {
            stage(cur ^ 1, k0 + 32);   // issue next tile, leave in flight
            asm volatile("s_waitcnt vmcnt(3)" ::: "memory");   // own cur-tile loads done
        } else {
            asm volatile("s_waitcnt vmcnt(0)" ::: "memory");
        }
        __builtin_amdgcn_s_barrier();
        asm volatile("" ::: "memory");
        bf16x8 af[4], bf[2];
#pragma unroll
        for (int mi = 0; mi < 4; mi++)
            af[mi] = *(const bf16x8*)&lds[cur * 4096 + (lg * 128 + wr * 64 + mi * 16 + lc) * 8];
#pragma unroll
        for (int ni = 0; ni < 2; ni++)
            bf[ni] = *(const bf16x8*)&lds[8192 + cur * 2048 + (lg * 64 + wc * 32 + ni * 16 + lc) * 8];
        __builtin_amdgcn_s_setprio(1);
#pragma unroll
        for (int mi = 0; mi < 4; mi++)
#pragma unroll
            for (int ni = 0; ni < 2; ni++)
                acc[mi][ni] = __builtin_amdgcn_mfma_f32_16x16x32_bf16(af[mi], bf[ni], acc[mi][ni], 0, 0, 0);
        __builtin_amdgcn_s_setprio(0);
        asm volatile("s_waitcnt lgkmcnt(0)" ::: "memory");
        __builtin_amdgcn_s_barrier();
        asm volatile("" ::: "memory");
    }
    if (isq) {
#pragma unroll
        for (int mi = 0; mi < 4; mi++)
#pragma unroll
            for (int ni = 0; ni < 2; ni++)
#pragma unroll
                for (int r = 0; r < 4; r++) {
                    int m = m0 + wr * 64 + mi * 16 + lg * 4 + r;
                    int n = n0 + wc * 32 + ni * 16 + lc;
                    qb[(size_t)m * 1024 + n] = f2b(acc[mi][ni][r] * qscale);
                }
    } else if (n0 < 1024) {      // k half: row-major (block-uniform)
#pragma unroll
        for (int mi = 0; mi < 4; mi++)
#pragma unroll
            for (int ni = 0; ni < 2; ni++)
#pragma unroll
                for (int r = 0; r < 4; r++) {
                    int m = m0 + wr * 64 + mi * 16 + lg * 4 + r;
                    int n = n0 + wc * 32 + ni * 16 + lc;
                    kb[(size_t)m * 1024 + n] = f2b(acc[mi][ni][r]);
                }
    } else {                     // v half: LDS transpose -> coalesced vtb[b][h][d][kv] stores
        // last K-iter ended with lgkmcnt(0)+barrier -> LDS free to reuse
        int b = m0 >> 11, kv0 = m0 & 2047;
        int h = (n0 - 1024) >> 6;                 // block covers exactly one head (64 n-cols)
#pragma unroll
        for (int mi = 0; mi < 4; mi++)
#pragma unroll
            for (int ni = 0; ni < 2; ni++)
#pragma unroll
                for (int r = 0; r < 4; r++) {
                    int ml = wr * 64 + mi * 16 + lg * 4 + r;    // kv-local
                    int nl = wc * 32 + ni * 16 + lc;            // d
                    lds[nl * 136 + ml] = f2b(acc[mi][ni][r]);
                }
        __syncthreads();
#pragma unroll
        for (int c = 0; c < 4; c++) {
            int d = t >> 2, chunk = (t & 3) + c * 4;
            u32x4 v = *(u32x4*)&lds[d * 136 + chunk * 8];
            *(u32x4*)&vtb[(((size_t)b * HEADS + h) * DH + d) * (size_t)NKV + kv0 + chunk * 8] = v;
        }
    }
}

// ---------------- out-proj GEMM: 512 blocks of 128x64, f32 out + bias ----------------
__global__ __launch_bounds__(256) void gemm_out(const ushort* __restrict__ A, const ushort* __restrict__ Bt,
                                                float* __restrict__ C0, const float* __restrict__ bias,
                                                int M, int N, int K) {
    __shared__ ushort As[2][4096];        // [kc4][row128][8]
    __shared__ ushort Bs[2][2048];        // [kc4][row64][8]
    int flat = blockIdx.x;
    int swz = (flat & 7) * 64 + (flat >> 3);      // XCD-chunked (512 % 8 == 0)
    int m0 = (swz >> 4) * 128, n0 = (swz & 15) * 64;
    int t = threadIdx.x, l = t & 63, w = t >> 6;
    int wr = w >> 1, wc = w & 1;
    int lg = l >> 4, lc = l & 15;
    f32x4 acc[4][2] = {};

    auto stage = [&](int buf, int k0) {
#pragma unroll
        for (int i = 0; i < 2; i++) {
            int s = w + i * 4;
            gload16(A + (size_t)(m0 + (s & 1) * 64 + l) * K + k0 + (s >> 1) * 8, &As[buf][s * 512]);
        }
        gload16(Bt + (size_t)(n0 + l) * K + k0 + w * 8, &Bs[buf][w * 512]);
    };

    stage(0, 0);
    for (int k0 = 0, tt = 0; k0 < K; k0 += 32, ++tt) {
        int cur = tt & 1;
        if (k0 + 32 < K) {
            stage(cur ^ 1, k0 + 32);
            asm volatile("s_waitcnt vmcnt(3)" ::: "memory");
        } else {
            asm volatile("s_waitcnt vmcnt(0)" ::: "memory");
        }
        __builtin_amdgcn_s_barrier();
        asm volatile("" ::: "memory");
        bf16x8 af[4], bf[2];
#pragma unroll
        for (int mi = 0; mi < 4; mi++)
            af[mi] = *(const bf16x8*)&As[cur][(lg * 128 + wr * 64 + mi * 16 + lc) * 8];
#pragma unroll
        for (int ni = 0; ni < 2; ni++)
            bf[ni] = *(const bf16x8*)&Bs[cur][(lg * 64 + wc * 32 + ni * 16 + lc) * 8];
        __builtin_amdgcn_s_setprio(1);
#pragma unroll
        for (int mi = 0; mi < 4; mi++)
#pragma unroll
            for (int ni = 0; ni < 2; ni++)
                acc[mi][ni] = __builtin_amdgcn_mfma_f32_16x16x32_bf16(af[mi], bf[ni], acc[mi][ni], 0, 0, 0);
        __builtin_amdgcn_s_setprio(0);
        asm volatile("s_waitcnt lgkmcnt(0)" ::: "memory");
        __builtin_amdgcn_s_barrier();
        asm volatile("" ::: "memory");
    }
#pragma unroll
    for (int mi = 0; mi < 4; mi++)
#pragma unroll
        for (int ni = 0; ni < 2; ni++)
#pragma unroll
            for (int r = 0; r < 4; r++) {
                int m = m0 + wr * 64 + mi * 16 + lg * 4 + r;
                int n = n0 + wc * 32 + ni * 16 + lc;
                C0[(size_t)m * N + n] = acc[mi][ni][r] + bias[n];
            }
}

// ---------------- flash attention: QBLK=128 (4 waves x 32 q), KVBLK=64 dbuf ----------------
// swapped QK^T, in-reg softmax (exp2) + defer-max, P aliases Q-LDS. qb pre-scaled 0.125*log2e.
__global__ __launch_bounds__(256, 3) void attn3(const ushort* __restrict__ qb, const ushort* __restrict__ kb,
                                                const ushort* __restrict__ vtb, ushort* __restrict__ ob) {
    __shared__ ushort Qs[8 * 128 * 8];   // [dc8][q128][8] 16KB; reused as P after Q consumed
    __shared__ ushort Ks[2][4096];       // [dc8][kv64][8]    16KB
    __shared__ ushort Vs[2][4096];       // [kvc8][d64][8]    16KB
    int flat = blockIdx.x;
    int swz = (flat & 7) * 64 + (flat >> 3);           // XCD-chunked (512 % 8 == 0)
    int qt = swz & 15, h = (swz >> 4) & 15, b = swz >> 8;
    int t = threadIdx.x, l = t & 63, w = t >> 6;
    int lg = l >> 4, lc = l & 15;
    int xsw = (lc << 1) & 0x1C;
    const ushort* Qg = qb + (size_t)b * NQ * INNER + h * DH;
    const ushort* Kg = kb + (size_t)b * NKV * INNER + h * DH;
    const ushort* Vg = vtb + (((size_t)b * HEADS + h) * DH) * NKV;
    int q0 = qt * 128;

    // stage Q (16 segments of 1KB)
#pragma unroll
    for (int i = 0; i < 4; i++) {
        int s = w * 4 + i;
        gload16(Qg + (size_t)(q0 + (s & 1) * 64 + l) * INNER + (s >> 1) * 8, &Qs[s * 512]);
    }
    auto stageKV = [&](int buf, int kv0) {
#pragma unroll
        for (int i = 0; i < 2; i++) {
            int s = w + i * 4;
            gload16(Kg + (size_t)(kv0 + l) * INNER + s * 8, &Ks[buf][s * 512]);
            gload16(Vg + (size_t)l * NKV + kv0 + s * 8, &Vs[buf][s * 512]);
        }
    };
    stageKV(0, 0);
    __syncthreads();

    bf16x8 qf[2][2];   // [mi][kc]: B-frag rows q = w*32 + mi*16 + lc
#pragma unroll
    for (int mi = 0; mi < 2; mi++)
#pragma unroll
        for (int kc = 0; kc < 2; kc++)
            qf[mi][kc] = *(const bf16x8*)&Qs[((kc * 4 + lg) * 128 + w * 32 + mi * 16 + lc) * 8];
    __syncthreads();   // all waves done reading Q before Qs is reused as P

    uint* Ps = (uint*)Qs + w * 1024;     // per-wave [q32][32 pair-words], swizzled (4KB)
    f32x4 o[2][4] = {};                  // O^T: [mi][nb d-block], row d = nb*16+lg*4+r, col q = lc
    float m_[2] = {-1e30f, -1e30f}, s_[2] = {0.f, 0.f};

    for (int tt = 0; tt < NKV / 64; ++tt) {
        int cur = tt & 1;
        if (tt + 1 < NKV / 64) stageKV(cur ^ 1, (tt + 1) * 64);
        // S^T[kv][q] = mfma(A=K rows, B=Q rows), in log2 units
        f32x4 st[2][4] = {};
        __builtin_amdgcn_s_setprio(1);
#pragma unroll
        for (int kc = 0; kc < 2; kc++)
#pragma unroll
            for (int nb = 0; nb < 4; nb++) {
                bf16x8 kf = *(const bf16x8*)&Ks[cur][((kc * 4 + lg) * 64 + nb * 16 + lc) * 8];
                st[0][nb] = __builtin_amdgcn_mfma_f32_16x16x32_bf16(kf, qf[0][kc], st[0][nb], 0, 0, 0);
                st[1][nb] = __builtin_amdgcn_mfma_f32_16x16x32_bf16(kf, qf[1][kc], st[1][nb], 0, 0, 0);
            }
        __builtin_amdgcn_s_setprio(0);
        // per-mi in-register online softmax (lane owns q = mi*16+lc; kv = nb*16+lg*4+r)
#pragma unroll
        for (int mi = 0; mi < 2; mi++) {
            float mx = st[mi][0][0];
#pragma unroll
            for (int nb = 0; nb < 4; nb++)
#pragma unroll
                for (int r = 0; r < 4; r++) mx = fmaxf(mx, st[mi][nb][r]);
            mx = fmaxf(mx, __shfl_xor(mx, 16));
            mx = fmaxf(mx, __shfl_xor(mx, 32));
            if (!__all(mx - m_[mi] <= 8.f)) {    // defer-max (T13): rescale only on real growth
                float mn = fmaxf(m_[mi], mx);
                float fac = __builtin_amdgcn_exp2f(m_[mi] - mn);
                m_[mi] = mn;
                s_[mi] *= fac;
#pragma unroll
                for (int nb = 0; nb < 4; nb++) o[mi][nb] *= fac;
            }
            float mn = m_[mi];
            float rs = 0.f;
#pragma unroll
            for (int nb = 0; nb < 4; nb++) {
                float p0 = __builtin_amdgcn_exp2f(st[mi][nb][0] - mn);
                float p1 = __builtin_amdgcn_exp2f(st[mi][nb][1] - mn);
                float p2 = __builtin_amdgcn_exp2f(st[mi][nb][2] - mn);
                float p3 = __builtin_amdgcn_exp2f(st[mi][nb][3] - mn);
                rs += (p0 + p1) + (p2 + p3);
                uint2 pw;
                pw.x = pkbf16(p0, p1);
                pw.y = pkbf16(p2, p3);
                *(uint2*)&Ps[(mi * 16 + lc) * 32 + ((nb * 8 + lg * 2) ^ xsw)] = pw;
            }
            rs += __shfl_xor(rs, 16);
            rs += __shfl_xor(rs, 32);
            s_[mi] += rs;
        }
        // compiler-level memory fence: forbid hoisting the P reads above the P writes
        asm volatile("" ::: "memory");
        // PV: O^T[d][q] += mfma(A=V^T rows d, B=P rows q)
        bf16x8 pf[2][2], vf[4][2];
#pragma unroll
        for (int mi = 0; mi < 2; mi++)
#pragma unroll
            for (int kc = 0; kc < 2; kc++)
                pf[mi][kc] = *(const bf16x8*)&Ps[(mi * 16 + lc) * 32 + ((kc * 16 + lg * 4) ^ xsw)];
#pragma unroll
        for (int nb = 0; nb < 4; nb++)
#pragma unroll
            for (int kc = 0; kc < 2; kc++)
                vf[nb][kc] = *(const bf16x8*)&Vs[cur][((kc * 4 + lg) * 64 + nb * 16 + lc) * 8];
        __builtin_amdgcn_s_setprio(1);
#pragma unroll
        for (int nb = 0; nb < 4; nb++)
#pragma unroll
            for (int kc = 0; kc < 2; kc++) {
                o[0][nb] = __builtin_amdgcn_mfma_f32_16x16x32_bf16(vf[nb][kc], pf[0][kc], o[0][nb], 0, 0, 0);
                o[1][nb] = __builtin_amdgcn_mfma_f32_16x16x32_bf16(vf[nb][kc], pf[1][kc], o[1][nb], 0, 0, 0);
            }
        __builtin_amdgcn_s_setprio(0);
        __syncthreads();
    }
    ushort* Og = ob + (size_t)b * NQ * INNER + h * DH;
#pragma unroll
    for (int mi = 0; mi < 2; mi++) {
        float inv = 1.f / s_[mi];
        int q = q0 + w * 32 + mi * 16 + lc;
#pragma unroll
        for (int nb = 0; nb < 4; nb++) {
            uint2 pw;
            pw.x = pkbf16(o[mi][nb][0] * inv, o[mi][nb][1] * inv);
            pw.y = pkbf16(o[mi][nb][2] * inv, o[mi][nb][3] * inv);
            *(uint2*)&Og[(size_t)q * INNER + nb * 16 + lg * 4] = pw;
        }
    }
}

extern "C" void kernel_launch(void* const* d_in, const int* in_sizes, int n_in,
                              void* d_out, int out_size, void* d_ws, size_t ws_size,
                              hipStream_t stream) {
    const float* x    = (const float*)d_in[0];
    const float* ctx  = (const float*)d_in[1];
    const float* Wq   = (const float*)d_in[2];
    const float* Wkv  = (const float*)d_in[3];
    const float* Wout = (const float*)d_in[4];
    const float* bout = (const float*)d_in[5];
    float* out = (float*)d_out;

    if (ws_size < (size_t)(56u << 20)) return;  // need 56MB scratch
    char* ws = (char*)d_ws;
    ushort* xb    = (ushort*)(ws);                 // 8MB
    ushort* cb    = (ushort*)(ws + (8u << 20));    // 8MB, dead after gemm_qkv
    ushort* ob    = (ushort*)(ws + (8u << 20));    // reuse cb slot
    ushort* qb    = (ushort*)(ws + (16u << 20));
    ushort* kb    = (ushort*)(ws + (24u << 20));
    ushort* vtb   = (ushort*)(ws + (32u << 20));   // v written directly transposed
    ushort* Wqt   = (ushort*)(ws + (48u << 20));
    ushort* Wkvt  = (ushort*)(ws + (50u << 20));
    ushort* Woutt = (ushort*)(ws + (54u << 20));

    prep<<<dim3(32, 32, 5), dim3(32, 8), 0, stream>>>(x, ctx, Wq, Wkv, Wout, xb, cb, Wqt, Wkvt, Woutt);
    // fused q-proj (scaled by 0.125*log2e) + kv-proj (v written transposed)
    gemm_qkv<<<1536, 256, 0, stream>>>(xb, cb, Wqt, Wkvt, qb, kb, vtb, 0.125f * 1.44269504f);
    attn3<<<512, 256, 0, stream>>>(qb, kb, vtb, ob);
    gemm_out<<<512, 256, 0, stream>>>(ob, Woutt, out, bout, 4096, 1024, 1024);
}

// Round 12
// 165.961 us; speedup vs baseline: 1.1891x; 1.1630x over previous
//
#include <hip/hip_runtime.h>
#include <hip/hip_bf16.h>
#include <stdint.h>

#define NQ 2048
#define NKV 2048
#define DIM 1024
#define INNER 1024
#define HEADS 16
#define DH 64
#define BATCH 2

typedef float f32x4 __attribute__((ext_vector_type(4)));
typedef __bf16 bf16x8 __attribute__((ext_vector_type(8)));
typedef unsigned int u32x4 __attribute__((ext_vector_type(4)));

__device__ inline ushort f2b(float f) {
    uint32_t u = __builtin_bit_cast(uint32_t, f);
    u += 0x7fff + ((u >> 16) & 1);   // round-to-nearest-even
    return (ushort)(u >> 16);
}

__device__ inline uint pkbf16(float lo, float hi) {
    __hip_bfloat162 h = __float22bfloat162_rn(make_float2(lo, hi));
    uint r;
    __builtin_memcpy(&r, &h, 4);   // low 16 = bf16(lo), high 16 = bf16(hi)
    return r;
}

__device__ __forceinline__ void gload16(const void* g, void* lds) {
    __builtin_amdgcn_global_load_lds(
        (const __attribute__((address_space(1))) unsigned int*)g,
        (__attribute__((address_space(3))) unsigned int*)lds, 16, 0, 0);
}

// ---------------- fused prep: z<4 -> weight transpose+cvt slices; z==4 -> x/ctx convert ----------------
__global__ void prep(const float* __restrict__ x, const float* __restrict__ ctx,
                     const float* __restrict__ Wq, const float* __restrict__ Wkv,
                     const float* __restrict__ Wout,
                     ushort* __restrict__ xb, ushort* __restrict__ cb,
                     ushort* __restrict__ Wqt, ushort* __restrict__ Wkvt,
                     ushort* __restrict__ Woutt) {
    int z = blockIdx.z;
    if (z < 4) {
        __shared__ ushort tile[32][33];
        const float* src; ushort* dst; int C;
        if (z == 0)      { src = Wq;          dst = Wqt;                C = 1024; }
        else if (z == 1) { src = Wkv;         dst = Wkvt;               C = 2048; }
        else if (z == 2) { src = Wkv + 1024;  dst = Wkvt + 1024 * 1024; C = 2048; }
        else             { src = Wout;        dst = Woutt;              C = 1024; }
        int c0 = blockIdx.x * 32, r0 = blockIdx.y * 32;
        int tx = threadIdx.x, ty = threadIdx.y;   // 32 x 8
#pragma unroll
        for (int i = 0; i < 4; i++)
            tile[ty + i * 8][tx] = f2b(src[(size_t)(r0 + ty + i * 8) * C + c0 + tx]);
        __syncthreads();
#pragma unroll
        for (int i = 0; i < 4; i++)
            dst[(size_t)(c0 + ty + i * 8) * 1024 + r0 + tx] = tile[tx][ty + i * 8];
    } else {
        const int n4 = (BATCH * NQ * DIM) / 4;   // float4 count per tensor
        int fb = blockIdx.y * 32 + blockIdx.x;   // 0..1023
        int t = threadIdx.y * 32 + threadIdx.x;  // 0..255
        for (int i = fb * 256 + t; i < 2 * n4; i += 1024 * 256) {
            float4 v;
            if (i < n4) v = ((const float4*)x)[i];
            else        v = ((const float4*)ctx)[i - n4];
            ushort4 o;
            o.x = f2b(v.x); o.y = f2b(v.y); o.z = f2b(v.z); o.w = f2b(v.w);
            if (i < n4) ((ushort4*)xb)[i] = o;
            else        ((ushort4*)cb)[i - n4] = o;
        }
    }
}

// ---------------- fused q/kv GEMM: 768 blocks of 128x128, K=1024, triple-buffer 2-deep prefetch ----------------
// swz < 256: qb = xb @ Wqt^T * qscale
// swz >= 256: kv = cb @ Wkvt^T; n<1024 -> kb row-major; n>=1024 -> vtb[b][h][d][kv] via LDS transpose
__global__ __launch_bounds__(256) void gemm_qkv(const ushort* __restrict__ xb, const ushort* __restrict__ cb,
                                                const ushort* __restrict__ Wqt, const ushort* __restrict__ Wkvt,
                                                ushort* __restrict__ qb, ushort* __restrict__ kb,
                                                ushort* __restrict__ vtb, float qscale) {
    constexpr int K = 1024, NT = 32;
    __shared__ ushort lds[24576];   // 48KB: 3 bufs x (A 8KB + B 8KB); v-epilogue tile [128][136] reuses
    int flat = blockIdx.x;
    int swz = (flat & 7) * 96 + (flat >> 3);      // XCD-chunked, bijective (768 % 8 == 0)
    bool isq = swz < 256;
    const ushort *A, *Bt;
    int m0, n0;
    if (isq) { A = xb; Bt = Wqt;  m0 = (swz >> 3) * 128;  n0 = (swz & 7) * 128; }
    else     { int b2 = swz - 256; A = cb; Bt = Wkvt; m0 = (b2 >> 4) * 128; n0 = (b2 & 15) * 128; }
    int t = threadIdx.x, l = t & 63, w = t >> 6;
    int wr = w >> 1, wc = w & 1;
    int lg = l >> 4, lc = l & 15;
    f32x4 acc[4][4] = {};

    auto stage = [&](int buf, int k0) {
#pragma unroll
        for (int i = 0; i < 2; i++) {
            int s = w + i * 4;
            gload16(A + (size_t)(m0 + (s & 1) * 64 + l) * K + k0 + (s >> 1) * 8, &lds[buf * 8192 + s * 512]);
            gload16(Bt + (size_t)(n0 + (s & 1) * 64 + l) * K + k0 + (s >> 1) * 8, &lds[buf * 8192 + 4096 + s * 512]);
        }
    };

    stage(0, 0);
    stage(1, 32);
    for (int tt = 0; tt < NT; ++tt) {
        int cur = tt % 3;
        if (tt + 2 < NT) {
            stage((tt + 2) % 3, (tt + 2) * 32);   // 2-deep prefetch, stays in flight
            asm volatile("s_waitcnt vmcnt(8)" ::: "memory");   // oldest 4 (cur tile) done
        } else if (tt + 1 < NT) {
            asm volatile("s_waitcnt vmcnt(4)" ::: "memory");
        } else {
            asm volatile("s_waitcnt vmcnt(0)" ::: "memory");
        }
        __builtin_amdgcn_s_barrier();
        asm volatile("" ::: "memory");
        bf16x8 af[4], bf[4];
#pragma unroll
        for (int mi = 0; mi < 4; mi++)
            af[mi] = *(const bf16x8*)&lds[cur * 8192 + (lg * 128 + wr * 64 + mi * 16 + lc) * 8];
#pragma unroll
        for (int ni = 0; ni < 4; ni++)
            bf[ni] = *(const bf16x8*)&lds[cur * 8192 + 4096 + (lg * 128 + wc * 64 + ni * 16 + lc) * 8];
        __builtin_amdgcn_s_setprio(1);
#pragma unroll
        for (int mi = 0; mi < 4; mi++)
#pragma unroll
            for (int ni = 0; ni < 4; ni++)
                acc[mi][ni] = __builtin_amdgcn_mfma_f32_16x16x32_bf16(af[mi], bf[ni], acc[mi][ni], 0, 0, 0);
        __builtin_amdgcn_s_setprio(0);
        asm volatile("s_waitcnt lgkmcnt(0)" ::: "memory");
        __builtin_amdgcn_s_barrier();
        asm volatile("" ::: "memory");
    }
    if (isq) {
#pragma unroll
        for (int mi = 0; mi < 4; mi++)
#pragma unroll
            for (int ni = 0; ni < 4; ni++)
#pragma unroll
                for (int r = 0; r < 4; r++) {
                    int m = m0 + wr * 64 + mi * 16 + lg * 4 + r;
                    int n = n0 + wc * 64 + ni * 16 + lc;
                    qb[(size_t)m * 1024 + n] = f2b(acc[mi][ni][r] * qscale);
                }
    } else if (n0 < 1024) {      // k half: row-major
#pragma unroll
        for (int mi = 0; mi < 4; mi++)
#pragma unroll
            for (int ni = 0; ni < 4; ni++)
#pragma unroll
                for (int r = 0; r < 4; r++) {
                    int m = m0 + wr * 64 + mi * 16 + lg * 4 + r;
                    int n = n0 + wc * 64 + ni * 16 + lc;
                    kb[(size_t)m * 1024 + n] = f2b(acc[mi][ni][r]);
                }
    } else {                     // v half: LDS transpose -> coalesced vtb[b][h][d][kv] stores
        // last K-iter ended with lgkmcnt(0)+barrier -> LDS free to reuse
        int b = m0 >> 11, kv0 = m0 & 2047;
        int h0 = (n0 - 1024) >> 6;                // block covers heads h0, h0+1
#pragma unroll
        for (int mi = 0; mi < 4; mi++)
#pragma unroll
            for (int ni = 0; ni < 4; ni++)
#pragma unroll
                for (int r = 0; r < 4; r++) {
                    int ml = wr * 64 + mi * 16 + lg * 4 + r;    // kv-local 0..127
                    int nl = wc * 64 + ni * 16 + lc;            // n-local 0..127
                    lds[nl * 136 + ml] = f2b(acc[mi][ni][r]);
                }
        __syncthreads();
#pragma unroll
        for (int c = 0; c < 8; c++) {
            int idx = c * 256 + t;            // 0..2047
            int rrow = idx >> 4;              // n-local 0..127
            int chunk = idx & 15;             // 16B chunk along kv
            int h = h0 + (rrow >> 6), d = rrow & 63;
            u32x4 v = *(u32x4*)&lds[rrow * 136 + chunk * 8];
            *(u32x4*)&vtb[(((size_t)b * HEADS + h) * DH + d) * (size_t)NKV + kv0 + chunk * 8] = v;
        }
    }
}

// ---------------- out-proj GEMM: 256 blocks of 128x128, triple-buffer 2-deep, f32 out + bias ----------------
__global__ __launch_bounds__(256) void gemm_out(const ushort* __restrict__ A, const ushort* __restrict__ Bt,
                                                float* __restrict__ C0, const float* __restrict__ bias) {
    constexpr int K = 1024, NT = 32;
    __shared__ ushort lds[24576];
    int flat = blockIdx.x;
    int swz = (flat & 7) * 32 + (flat >> 3);      // XCD-chunked (256 % 8 == 0)
    int m0 = (swz >> 3) * 128, n0 = (swz & 7) * 128;
    int t = threadIdx.x, l = t & 63, w = t >> 6;
    int wr = w >> 1, wc = w & 1;
    int lg = l >> 4, lc = l & 15;
    f32x4 acc[4][4] = {};

    auto stage = [&](int buf, int k0) {
#pragma unroll
        for (int i = 0; i < 2; i++) {
            int s = w + i * 4;
            gload16(A + (size_t)(m0 + (s & 1) * 64 + l) * K + k0 + (s >> 1) * 8, &lds[buf * 8192 + s * 512]);
            gload16(Bt + (size_t)(n0 + (s & 1) * 64 + l) * K + k0 + (s >> 1) * 8, &lds[buf * 8192 + 4096 + s * 512]);
        }
    };

    stage(0, 0);
    stage(1, 32);
    for (int tt = 0; tt < NT; ++tt) {
        int cur = tt % 3;
        if (tt + 2 < NT) {
            stage((tt + 2) % 3, (tt + 2) * 32);
            asm volatile("s_waitcnt vmcnt(8)" ::: "memory");
        } else if (tt + 1 < NT) {
            asm volatile("s_waitcnt vmcnt(4)" ::: "memory");
        } else {
            asm volatile("s_waitcnt vmcnt(0)" ::: "memory");
        }
        __builtin_amdgcn_s_barrier();
        asm volatile("" ::: "memory");
        bf16x8 af[4], bf[4];
#pragma unroll
        for (int mi = 0; mi < 4; mi++)
            af[mi] = *(const bf16x8*)&lds[cur * 8192 + (lg * 128 + wr * 64 + mi * 16 + lc) * 8];
#pragma unroll
        for (int ni = 0; ni < 4; ni++)
            bf[ni] = *(const bf16x8*)&lds[cur * 8192 + 4096 + (lg * 128 + wc * 64 + ni * 16 + lc) * 8];
        __builtin_amdgcn_s_setprio(1);
#pragma unroll
        for (int mi = 0; mi < 4; mi++)
#pragma unroll
            for (int ni = 0; ni < 4; ni++)
                acc[mi][ni] = __builtin_amdgcn_mfma_f32_16x16x32_bf16(af[mi], bf[ni], acc[mi][ni], 0, 0, 0);
        __builtin_amdgcn_s_setprio(0);
        asm volatile("s_waitcnt lgkmcnt(0)" ::: "memory");
        __builtin_amdgcn_s_barrier();
        asm volatile("" ::: "memory");
    }
#pragma unroll
    for (int mi = 0; mi < 4; mi++)
#pragma unroll
        for (int ni = 0; ni < 4; ni++)
#pragma unroll
            for (int r = 0; r < 4; r++) {
                int m = m0 + wr * 64 + mi * 16 + lg * 4 + r;
                int n = n0 + wc * 64 + ni * 16 + lc;
                C0[(size_t)m * 1024 + n] = acc[mi][ni][r] + bias[n];
            }
}

// ---------------- flash attention: QBLK=128 (4 waves x 32 q), KVBLK=64 dbuf ----------------
// swapped QK^T, in-reg softmax (exp2) + defer-max, P aliases Q-LDS. qb pre-scaled 0.125*log2e.
__global__ __launch_bounds__(256, 3) void attn3(const ushort* __restrict__ qb, const ushort* __restrict__ kb,
                                                const ushort* __restrict__ vtb, ushort* __restrict__ ob) {
    __shared__ ushort Qs[8 * 128 * 8];   // [dc8][q128][8] 16KB; reused as P after Q consumed
    __shared__ ushort Ks[2][4096];       // [dc8][kv64][8]    16KB
    __shared__ ushort Vs[2][4096];       // [kvc8][d64][8]    16KB
    int flat = blockIdx.x;
    int swz = (flat & 7) * 64 + (flat >> 3);           // XCD-chunked (512 % 8 == 0)
    int qt = swz & 15, h = (swz >> 4) & 15, b = swz >> 8;
    int t = threadIdx.x, l = t & 63, w = t >> 6;
    int lg = l >> 4, lc = l & 15;
    int xsw = (lc << 1) & 0x1C;
    const ushort* Qg = qb + (size_t)b * NQ * INNER + h * DH;
    const ushort* Kg = kb + (size_t)b * NKV * INNER + h * DH;
    const ushort* Vg = vtb + (((size_t)b * HEADS + h) * DH) * NKV;
    int q0 = qt * 128;

    // stage Q (16 segments of 1KB)
#pragma unroll
    for (int i = 0; i < 4; i++) {
        int s = w * 4 + i;
        gload16(Qg + (size_t)(q0 + (s & 1) * 64 + l) * INNER + (s >> 1) * 8, &Qs[s * 512]);
    }
    auto stageKV = [&](int buf, int kv0) {
#pragma unroll
        for (int i = 0; i < 2; i++) {
            int s = w + i * 4;
            gload16(Kg + (size_t)(kv0 + l) * INNER + s * 8, &Ks[buf][s * 512]);
            gload16(Vg + (size_t)l * NKV + kv0 + s * 8, &Vs[buf][s * 512]);
        }
    };
    stageKV(0, 0);
    __syncthreads();

    bf16x8 qf[2][2];   // [mi][kc]: B-frag rows q = w*32 + mi*16 + lc
#pragma unroll
    for (int mi = 0; mi < 2; mi++)
#pragma unroll
        for (int kc = 0; kc < 2; kc++)
            qf[mi][kc] = *(const bf16x8*)&Qs[((kc * 4 + lg) * 128 + w * 32 + mi * 16 + lc) * 8];
    __syncthreads();   // all waves done reading Q before Qs is reused as P

    uint* Ps = (uint*)Qs + w * 1024;     // per-wave [q32][32 pair-words], swizzled (4KB)
    f32x4 o[2][4] = {};                  // O^T: [mi][nb d-block], row d = nb*16+lg*4+r, col q = lc
    float m_[2] = {-1e30f, -1e30f}, s_[2] = {0.f, 0.f};

    for (int tt = 0; tt < NKV / 64; ++tt) {
        int cur = tt & 1;
        if (tt + 1 < NKV / 64) stageKV(cur ^ 1, (tt + 1) * 64);
        // S^T[kv][q] = mfma(A=K rows, B=Q rows), in log2 units
        f32x4 st[2][4] = {};
        __builtin_amdgcn_s_setprio(1);
#pragma unroll
        for (int kc = 0; kc < 2; kc++)
#pragma unroll
            for (int nb = 0; nb < 4; nb++) {
                bf16x8 kf = *(const bf16x8*)&Ks[cur][((kc * 4 + lg) * 64 + nb * 16 + lc) * 8];
                st[0][nb] = __builtin_amdgcn_mfma_f32_16x16x32_bf16(kf, qf[0][kc], st[0][nb], 0, 0, 0);
                st[1][nb] = __builtin_amdgcn_mfma_f32_16x16x32_bf16(kf, qf[1][kc], st[1][nb], 0, 0, 0);
            }
        __builtin_amdgcn_s_setprio(0);
        // per-mi in-register online softmax (lane owns q = mi*16+lc; kv = nb*16+lg*4+r)
#pragma unroll
        for (int mi = 0; mi < 2; mi++) {
            float mx = st[mi][0][0];
#pragma unroll
            for (int nb = 0; nb < 4; nb++)
#pragma unroll
                for (int r = 0; r < 4; r++) mx = fmaxf(mx, st[mi][nb][r]);
            mx = fmaxf(mx, __shfl_xor(mx, 16));
            mx = fmaxf(mx, __shfl_xor(mx, 32));
            if (!__all(mx - m_[mi] <= 8.f)) {    // defer-max (T13): rescale only on real growth
                float mn = fmaxf(m_[mi], mx);
                float fac = __builtin_amdgcn_exp2f(m_[mi] - mn);
                m_[mi] = mn;
                s_[mi] *= fac;
#pragma unroll
                for (int nb = 0; nb < 4; nb++) o[mi][nb] *= fac;
            }
            float mn = m_[mi];
            float rs = 0.f;
#pragma unroll
            for (int nb = 0; nb < 4; nb++) {
                float p0 = __builtin_amdgcn_exp2f(st[mi][nb][0] - mn);
                float p1 = __builtin_amdgcn_exp2f(st[mi][nb][1] - mn);
                float p2 = __builtin_amdgcn_exp2f(st[mi][nb][2] - mn);
                float p3 = __builtin_amdgcn_exp2f(st[mi][nb][3] - mn);
                rs += (p0 + p1) + (p2 + p3);
                uint2 pw;
                pw.x = pkbf16(p0, p1);
                pw.y = pkbf16(p2, p3);
                *(uint2*)&Ps[(mi * 16 + lc) * 32 + ((nb * 8 + lg * 2) ^ xsw)] = pw;
            }
            rs += __shfl_xor(rs, 16);
            rs += __shfl_xor(rs, 32);
            s_[mi] += rs;
        }
        // compiler-level memory fence: forbid hoisting the P reads above the P writes
        asm volatile("" ::: "memory");
        // PV: O^T[d][q] += mfma(A=V^T rows d, B=P rows q)
        bf16x8 pf[2][2], vf[4][2];
#pragma unroll
        for (int mi = 0; mi < 2; mi++)
#pragma unroll
            for (int kc = 0; kc < 2; kc++)
                pf[mi][kc] = *(const bf16x8*)&Ps[(mi * 16 + lc) * 32 + ((kc * 16 + lg * 4) ^ xsw)];
#pragma unroll
        for (int nb = 0; nb < 4; nb++)
#pragma unroll
            for (int kc = 0; kc < 2; kc++)
                vf[nb][kc] = *(const bf16x8*)&Vs[cur][((kc * 4 + lg) * 64 + nb * 16 + lc) * 8];
        __builtin_amdgcn_s_setprio(1);
#pragma unroll
        for (int nb = 0; nb < 4; nb++)
#pragma unroll
            for (int kc = 0; kc < 2; kc++) {
                o[0][nb] = __builtin_amdgcn_mfma_f32_16x16x32_bf16(vf[nb][kc], pf[0][kc], o[0][nb], 0, 0, 0);
                o[1][nb] = __builtin_amdgcn_mfma_f32_16x16x32_bf16(vf[nb][kc], pf[1][kc], o[1][nb], 0, 0, 0);
            }
        __builtin_amdgcn_s_setprio(0);
        __syncthreads();
    }
    ushort* Og = ob + (size_t)b * NQ * INNER + h * DH;
#pragma unroll
    for (int mi = 0; mi < 2; mi++) {
        float inv = 1.f / s_[mi];
        int q = q0 + w * 32 + mi * 16 + lc;
#pragma unroll
        for (int nb = 0; nb < 4; nb++) {
            uint2 pw;
            pw.x = pkbf16(o[mi][nb][0] * inv, o[mi][nb][1] * inv);
            pw.y = pkbf16(o[mi][nb][2] * inv, o[mi][nb][3] * inv);
            *(uint2*)&Og[(size_t)q * INNER + nb * 16 + lg * 4] = pw;
        }
    }
}

extern "C" void kernel_launch(void* const* d_in, const int* in_sizes, int n_in,
                              void* d_out, int out_size, void* d_ws, size_t ws_size,
                              hipStream_t stream) {
    const float* x    = (const float*)d_in[0];
    const float* ctx  = (const float*)d_in[1];
    const float* Wq   = (const float*)d_in[2];
    const float* Wkv  = (const float*)d_in[3];
    const float* Wout = (const float*)d_in[4];
    const float* bout = (const float*)d_in[5];
    float* out = (float*)d_out;

    if (ws_size < (size_t)(56u << 20)) return;  // need 56MB scratch
    char* ws = (char*)d_ws;
    ushort* xb    = (ushort*)(ws);                 // 8MB
    ushort* cb    = (ushort*)(ws + (8u << 20));    // 8MB, dead after gemm_qkv
    ushort* ob    = (ushort*)(ws + (8u << 20));    // reuse cb slot
    ushort* qb    = (ushort*)(ws + (16u << 20));
    ushort* kb    = (ushort*)(ws + (24u << 20));
    ushort* vtb   = (ushort*)(ws + (32u << 20));   // v written directly transposed
    ushort* Wqt   = (ushort*)(ws + (48u << 20));
    ushort* Wkvt  = (ushort*)(ws + (50u << 20));
    ushort* Woutt = (ushort*)(ws + (54u << 20));

    prep<<<dim3(32, 32, 5), dim3(32, 8), 0, stream>>>(x, ctx, Wq, Wkv, Wout, xb, cb, Wqt, Wkvt, Woutt);
    // fused q-proj (scaled by 0.125*log2e) + kv-proj (v written transposed)
    gemm_qkv<<<768, 256, 0, stream>>>(xb, cb, Wqt, Wkvt, qb, kb, vtb, 0.125f * 1.44269504f);
    attn3<<<512, 256, 0, stream>>>(qb, kb, vtb, ob);
    gemm_out<<<256, 256, 0, stream>>>(ob, Woutt, out, bout);
}